// Round 1
// baseline (592.050 us; speedup 1.0000x reference)
//
#include <hip/hip_runtime.h>
#include <hip/hip_bf16.h>
#include <cstdint>
#include <cstddef>

// ---- problem constants (shapes fixed by the reference) ----
#define NGROUP 2048          // B*T*K
#define NROW   96            // P*J
#define DDIM   256
#define SCALE1 0.17677669529663687f   // 1/sqrt(32)
#define POSE_ELEMS 50331648ll         // B*T*K*P*J*D
#define QNS    264           // padded bf16 row stride (16B aligned, kills bank conflicts)

typedef __attribute__((ext_vector_type(8))) short bf16x8;
typedef __attribute__((ext_vector_type(4))) float f32x4;

__device__ __forceinline__ unsigned short f2b(float f){
    unsigned int u = __float_as_uint(f);
    u = (u + 0x7FFFu + ((u >> 16) & 1u)) >> 16;   // RNE
    return (unsigned short)u;
}
__device__ __forceinline__ float b2f(unsigned short s){
    return __uint_as_float(((unsigned int)s) << 16);
}
__device__ __forceinline__ float wredsum(float v){
    #pragma unroll
    for (int m = 1; m < 64; m <<= 1) v += __shfl_xor(v, m);
    return v;
}

// ---------- K0: convert weights to bf16 (wq1, wo1, wo2^T, wv2^T) ----------
__global__ __launch_bounds__(256) void k_conv(
    const float* __restrict__ wqkv1, const float* __restrict__ wo1,
    const float* __restrict__ wqkv2, const float* __restrict__ wo2,
    unsigned short* __restrict__ wq1b, unsigned short* __restrict__ wo1b,
    unsigned short* __restrict__ wo2Tb, unsigned short* __restrict__ wv2Tb)
{
    int t = blockIdx.x * 256 + threadIdx.x;     // 65536 total
    wq1b[t] = f2b(wqkv1[t]);                    // wq1 = rows 0..255 of w_qkv1
    wo1b[t] = f2b(wo1[t]);
    int rr = t >> 8, cc = t & 255;
    wo2Tb[t] = f2b(wo2[cc * 256 + rr]);                  // wo2T[m][c] = wo2[c][m]
    wv2Tb[t] = f2b(wqkv2[(512 + cc) * 256 + rr]);        // wv2T[i][m] = wv2[m][i]
}

// ---------- K1: camera-side prep: kc, vc (stage1 K/V), u = Wk2^T q2 (stage2) ----------
__global__ __launch_bounds__(256) void k_camprep(
    const float* __restrict__ cam, const float* __restrict__ ln2g, const float* __restrict__ ln2b,
    const float* __restrict__ wqkv1, const float* __restrict__ bqkv1,
    const float* __restrict__ wqkv2, const float* __restrict__ bqkv2,
    float* __restrict__ kcw, float* __restrict__ vcw, float* __restrict__ uw)
{
    __shared__ float c[8][256];
    __shared__ float cn[8][256];
    __shared__ float q2[8][256];
    int tid = threadIdx.x;
    int r0 = blockIdx.x * 8;                    // 8 camera rows per block
    for (int e = tid; e < 2048; e += 256) ((float*)c)[e] = cam[(size_t)r0*256 + e];
    __syncthreads();
    int wid = tid >> 6, lane = tid & 63;
    for (int r = wid; r < 8; r += 4){
        int j = lane * 4;
        float v0=c[r][j], v1=c[r][j+1], v2=c[r][j+2], v3=c[r][j+3];
        float s  = wredsum(v0+v1+v2+v3);
        float s2 = wredsum(v0*v0+v1*v1+v2*v2+v3*v3);
        float mu = s * (1.f/256.f);
        float rs = rsqrtf(s2*(1.f/256.f) - mu*mu + 1e-5f);
        cn[r][j]   = (v0-mu)*rs*ln2g[j]   + ln2b[j];
        cn[r][j+1] = (v1-mu)*rs*ln2g[j+1] + ln2b[j+1];
        cn[r][j+2] = (v2-mu)*rs*ln2g[j+2] + ln2b[j+2];
        cn[r][j+3] = (v3-mu)*rs*ln2g[j+3] + ln2b[j+3];
    }
    __syncthreads();
    int j = tid;
    // q2[r][j] = LN(cam) @ wq2^T + bq2
    {
        float acc[8] = {0,0,0,0,0,0,0,0};
        const float4* wr = (const float4*)(wqkv2 + (size_t)j*256);
        for (int i4 = 0; i4 < 64; i4++){
            float4 w = wr[i4]; int i = i4*4;
            #pragma unroll
            for (int r = 0; r < 8; r++)
                acc[r] += cn[r][i]*w.x + cn[r][i+1]*w.y + cn[r][i+2]*w.z + cn[r][i+3]*w.w;
        }
        float bq = bqkv2[j];
        for (int r = 0; r < 8; r++) q2[r][j] = acc[r] + bq;
    }
    // kc/vc from RAW camera (no LN in reference for stage-1 K/V)
    {
        float ak[8] = {0,0,0,0,0,0,0,0}, av[8] = {0,0,0,0,0,0,0,0};
        const float4* wkr = (const float4*)(wqkv1 + (size_t)(256+j)*256);
        const float4* wvr = (const float4*)(wqkv1 + (size_t)(512+j)*256);
        for (int i4 = 0; i4 < 64; i4++){
            float4 wk = wkr[i4], wv = wvr[i4]; int i = i4*4;
            #pragma unroll
            for (int r = 0; r < 8; r++){
                ak[r] += c[r][i]*wk.x + c[r][i+1]*wk.y + c[r][i+2]*wk.z + c[r][i+3]*wk.w;
                av[r] += c[r][i]*wv.x + c[r][i+1]*wv.y + c[r][i+2]*wv.z + c[r][i+3]*wv.w;
            }
        }
        float bk = bqkv1[256+j], bv = bqkv1[512+j];
        for (int r = 0; r < 8; r++){
            kcw[(size_t)(r0+r)*256 + j] = ak[r] + bk;
            vcw[(size_t)(r0+r)*256 + j] = av[r] + bv;
        }
    }
    __syncthreads();
    // u[g][h][i] = sum_d q2[g][h*32+d] * wk2[h*32+d][i]   (bk2 dropped: cancels in softmax)
    {
        int i = tid;
        for (int h = 0; h < 8; h++){
            float acc[8] = {0,0,0,0,0,0,0,0};
            for (int d = 0; d < 32; d++){
                float w = wqkv2[(size_t)(256 + h*32 + d)*256 + i];
                #pragma unroll
                for (int r = 0; r < 8; r++) acc[r] += q2[r][h*32+d] * w;
            }
            for (int r = 0; r < 8; r++) uw[((size_t)(r0+r)*8 + h)*256 + i] = acc[r];
        }
    }
}

// ---------- K2: fused per-(b,t,k) block: stage1 + stage2 ----------
__global__ __launch_bounds__(512) void k_main(
    const float* __restrict__ pose, const float* __restrict__ cam,
    const float* __restrict__ ln1g, const float* __restrict__ ln1b,
    const float* __restrict__ bqkv1, const float* __restrict__ bo1,
    const float* __restrict__ bqkv2, const float* __restrict__ bo2,
    const unsigned short* __restrict__ wq1b, const unsigned short* __restrict__ wo1b,
    const unsigned short* __restrict__ wo2Tb, const unsigned short* __restrict__ wv2Tb,
    const float* __restrict__ kcw, const float* __restrict__ vcw, const float* __restrict__ uw,
    float* __restrict__ out)
{
    __shared__ unsigned short qn[NROW][QNS];   // LN(pose) bf16, then attn1 output o
    __shared__ unsigned short qb[NROW][QNS];   // q bf16, then pose_out bf16
    __shared__ float kcs[8][256];
    __shared__ float vcs[8][256];
    __shared__ float us[8][QNS];
    __shared__ float ys[8][QNS];
    __shared__ float sc[8][96];
    __shared__ float o2s[256];

    int tid = threadIdx.x;
    int g = blockIdx.x;            // (b*T+t)*K + k
    int bt = g >> 3;
    int wid = tid >> 6, lane = tid & 63;

    // P0: stage kc/vc (this b,t) and u (this g) into LDS
    for (int e = tid; e < 2048; e += 512){
        kcs[e>>8][e&255] = kcw[(size_t)bt*2048 + e];
        vcs[e>>8][e&255] = vcw[(size_t)bt*2048 + e];
        us[e>>8][e&255]  = uw[(size_t)g*2048 + e];
    }

    // P1: load pose rows, LN -> qn (bf16). wave w owns rows w, w+8, ...
    {
        float4 g1 = ((const float4*)ln1g)[lane];
        float4 b1 = ((const float4*)ln1b)[lane];
        float4 xv[12];
        #pragma unroll
        for (int rr = 0; rr < 12; rr++)
            xv[rr] = ((const float4*)(pose + ((size_t)g*96 + wid + rr*8)*256))[lane];
        #pragma unroll
        for (int rr = 0; rr < 12; rr++){
            int r = wid + rr*8;
            float4 f = xv[rr];
            float s  = wredsum(f.x+f.y+f.z+f.w);
            float s2 = wredsum(f.x*f.x+f.y*f.y+f.z*f.z+f.w*f.w);
            float mu = s * (1.f/256.f);
            float rs = rsqrtf(s2*(1.f/256.f) - mu*mu + 1e-5f);
            ushort4 qv;
            qv.x = f2b((f.x-mu)*rs*g1.x + b1.x);
            qv.y = f2b((f.y-mu)*rs*g1.y + b1.y);
            qv.z = f2b((f.z-mu)*rs*g1.z + b1.z);
            qv.w = f2b((f.w-mu)*rs*g1.w + b1.w);
            *(ushort4*)&qn[r][lane*4] = qv;
        }
    }
    __syncthreads();

    int wm = wid >> 2, wn = wid & 3;        // 2x4 wave grid over (M=96, N=256)
    int fr = lane & 15, fk = (lane >> 4) * 8;

    // P2: GEMM1  q = qn @ wq1^T + bq1  -> qb (bf16)
    {
        f32x4 acc[3][4];
        #pragma unroll
        for (int mt = 0; mt < 3; mt++)
            #pragma unroll
            for (int nt = 0; nt < 4; nt++) acc[mt][nt] = (f32x4){0.f,0.f,0.f,0.f};
        float bias[4];
        #pragma unroll
        for (int nt = 0; nt < 4; nt++) bias[nt] = bqkv1[wn*64 + nt*16 + fr];
        for (int k0 = 0; k0 < 256; k0 += 32){
            bf16x8 a[3], bfr[4];
            #pragma unroll
            for (int mt = 0; mt < 3; mt++)
                a[mt] = *(const bf16x8*)&qn[wm*48 + mt*16 + fr][k0 + fk];
            #pragma unroll
            for (int nt = 0; nt < 4; nt++)
                bfr[nt] = *(const bf16x8*)&wq1b[(size_t)(wn*64 + nt*16 + fr)*256 + k0 + fk];
            #pragma unroll
            for (int mt = 0; mt < 3; mt++)
                #pragma unroll
                for (int nt = 0; nt < 4; nt++)
                    acc[mt][nt] = __builtin_amdgcn_mfma_f32_16x16x32_bf16(a[mt], bfr[nt], acc[mt][nt], 0, 0, 0);
        }
        #pragma unroll
        for (int mt = 0; mt < 3; mt++)
            #pragma unroll
            for (int nt = 0; nt < 4; nt++){
                int col = wn*64 + nt*16 + fr;
                int rb  = wm*48 + mt*16 + (lane>>4)*4;
                #pragma unroll
                for (int i = 0; i < 4; i++)
                    qb[rb+i][col] = f2b(acc[mt][nt][i] + bias[nt]);
            }
    }
    __syncthreads();

    // P3: attention-1 per (row, head): 8-key softmax over camera tokens -> o into qn
    for (int task = tid; task < 768; task += 512){
        int h = task / 96, r = task % 96;
        float qv[32];
        const unsigned int* qrow = (const unsigned int*)&qb[r][h*32];
        #pragma unroll
        for (int jj = 0; jj < 16; jj++){
            unsigned int p = qrow[jj];
            qv[jj*2]   = b2f((unsigned short)(p & 0xFFFFu));
            qv[jj*2+1] = b2f((unsigned short)(p >> 16));
        }
        float s[8];
        #pragma unroll
        for (int kk = 0; kk < 8; kk++){
            float a = 0.f;
            #pragma unroll
            for (int jx = 0; jx < 32; jx++) a += qv[jx] * kcs[kk][h*32+jx];
            s[kk] = a * SCALE1;
        }
        float mx = s[0];
        #pragma unroll
        for (int kk = 1; kk < 8; kk++) mx = fmaxf(mx, s[kk]);
        float sum = 0.f;
        #pragma unroll
        for (int kk = 0; kk < 8; kk++){ s[kk] = __expf(s[kk]-mx); sum += s[kk]; }
        float inv = 1.f / sum;
        float o[32];
        #pragma unroll
        for (int jx = 0; jx < 32; jx++) o[jx] = 0.f;
        #pragma unroll
        for (int kk = 0; kk < 8; kk++){
            float a = s[kk] * inv;
            #pragma unroll
            for (int jx = 0; jx < 32; jx++) o[jx] += a * vcs[kk][h*32+jx];
        }
        unsigned int* orow = (unsigned int*)&qn[r][h*32];
        #pragma unroll
        for (int jj = 0; jj < 16; jj++)
            orow[jj] = (unsigned int)f2b(o[jj*2]) | ((unsigned int)f2b(o[jj*2+1]) << 16);
    }
    __syncthreads();

    // P4: GEMM2  o @ wo1^T + bo1 + residual -> out (fp32) and qb (bf16 pose_out)
    {
        f32x4 acc[3][4];
        #pragma unroll
        for (int mt = 0; mt < 3; mt++)
            #pragma unroll
            for (int nt = 0; nt < 4; nt++) acc[mt][nt] = (f32x4){0.f,0.f,0.f,0.f};
        float bias[4];
        #pragma unroll
        for (int nt = 0; nt < 4; nt++) bias[nt] = bo1[wn*64 + nt*16 + fr];
        for (int k0 = 0; k0 < 256; k0 += 32){
            bf16x8 a[3], bfr[4];
            #pragma unroll
            for (int mt = 0; mt < 3; mt++)
                a[mt] = *(const bf16x8*)&qn[wm*48 + mt*16 + fr][k0 + fk];
            #pragma unroll
            for (int nt = 0; nt < 4; nt++)
                bfr[nt] = *(const bf16x8*)&wo1b[(size_t)(wn*64 + nt*16 + fr)*256 + k0 + fk];
            #pragma unroll
            for (int mt = 0; mt < 3; mt++)
                #pragma unroll
                for (int nt = 0; nt < 4; nt++)
                    acc[mt][nt] = __builtin_amdgcn_mfma_f32_16x16x32_bf16(a[mt], bfr[nt], acc[mt][nt], 0, 0, 0);
        }
        #pragma unroll
        for (int mt = 0; mt < 3; mt++)
            #pragma unroll
            for (int nt = 0; nt < 4; nt++){
                int col = wn*64 + nt*16 + fr;
                int rb  = wm*48 + mt*16 + (lane>>4)*4;
                #pragma unroll
                for (int i = 0; i < 4; i++){
                    int row = rb + i;
                    size_t gi = ((size_t)g*96 + row)*256 + col;
                    float val = acc[mt][nt][i] + bias[nt] + pose[gi];
                    out[gi] = val;
                    qb[row][col] = f2b(val);
                }
            }
    }
    __syncthreads();

    // P6: stage-2 scores  s[h][n] = SCALE * u_h . pose_out_n
    {
        int h = tid & 7, n = tid >> 3;
        const unsigned int* xr = (const unsigned int*)&qb[n][0];
        float a = 0.f;
        for (int jj = 0; jj < 128; jj++){
            unsigned int p = xr[jj];
            a += us[h][jj*2]   * b2f((unsigned short)(p & 0xFFFFu))
               + us[h][jj*2+1] * b2f((unsigned short)(p >> 16));
        }
        sc[h][n] = a * SCALE1;
        if (tid < 256){
            int n2 = 64 + (tid >> 3);
            const unsigned int* xr2 = (const unsigned int*)&qb[n2][0];
            float a2 = 0.f;
            for (int jj = 0; jj < 128; jj++){
                unsigned int p = xr2[jj];
                a2 += us[h][jj*2]   * b2f((unsigned short)(p & 0xFFFFu))
                    + us[h][jj*2+1] * b2f((unsigned short)(p >> 16));
            }
            sc[h][n2] = a2 * SCALE1;
        }
    }
    __syncthreads();

    // P7: softmax over n=96 (wave wid owns head wid)
    {
        int hh = wid;
        float v0 = sc[hh][lane];
        float v1 = (lane < 32) ? sc[hh][64+lane] : -1e30f;
        float mx = fmaxf(v0, v1);
        #pragma unroll
        for (int m = 1; m < 64; m <<= 1) mx = fmaxf(mx, __shfl_xor(mx, m));
        float e0 = __expf(v0 - mx);
        float e1 = (lane < 32) ? __expf(v1 - mx) : 0.f;
        float sum = wredsum(e0 + e1);
        float inv = 1.f / sum;
        sc[hh][lane] = e0 * inv;
        if (lane < 32) sc[hh][64+lane] = e1 * inv;
    }
    __syncthreads();

    // P8: y[h][j] = sum_n a[h][n] * pose_out[n][j]
    {
        int jcol = tid & 255;
        for (int h = tid >> 8; h < 8; h += 2){
            float a = 0.f;
            for (int n = 0; n < 96; n++) a += sc[h][n] * b2f(qb[n][jcol]);
            ys[h][jcol] = a;
        }
    }
    __syncthreads();

    // P9: o2[m] = bv2[m] + Wv2[m,:] . y[m/32]
    if (tid < 256){
        int m = tid, h = m >> 5;
        float a = bqkv2[512 + m];
        for (int i = 0; i < 256; i++) a += b2f(wv2Tb[i*256 + m]) * ys[h][i];
        o2s[m] = a;
    }
    __syncthreads();

    // P10: cam_out = cam + b_o2 + o2 @ wo2^T
    if (tid < 256){
        int ccol = tid;
        float a = bo2[ccol] + cam[(size_t)g*256 + ccol];
        for (int m = 0; m < 256; m++) a += o2s[m] * b2f(wo2Tb[m*256 + ccol]);
        out[POSE_ELEMS + (size_t)g*256 + ccol] = a;
    }
}

extern "C" void kernel_launch(void* const* d_in, const int* in_sizes, int n_in,
                              void* d_out, int out_size, void* d_ws, size_t ws_size,
                              hipStream_t stream)
{
    const float* pose  = (const float*)d_in[0];
    const float* camr  = (const float*)d_in[1];
    const float* ln1g  = (const float*)d_in[2];
    const float* ln1b  = (const float*)d_in[3];
    const float* wqkv1 = (const float*)d_in[4];
    const float* bqkv1 = (const float*)d_in[5];
    const float* wo1   = (const float*)d_in[6];
    const float* bo1   = (const float*)d_in[7];
    const float* ln2g  = (const float*)d_in[8];
    const float* ln2b  = (const float*)d_in[9];
    const float* wqkv2 = (const float*)d_in[10];
    const float* bqkv2 = (const float*)d_in[11];
    const float* wo2   = (const float*)d_in[12];
    const float* bo2   = (const float*)d_in[13];
    float* out = (float*)d_out;
    char* ws = (char*)d_ws;

    unsigned short* wq1b  = (unsigned short*)ws;          // 65536 bf16
    unsigned short* wo1b  = wq1b + 65536;
    unsigned short* wo2Tb = wo1b + 65536;
    unsigned short* wv2Tb = wo2Tb + 65536;
    float* kcw = (float*)(ws + 524288);                   // 2048*256 f32
    float* vcw = kcw + 2048*256;
    float* uw  = vcw + 2048*256;                          // 2048*8*256 f32 (16 MB)

    k_conv<<<dim3(256), dim3(256), 0, stream>>>(wqkv1, wo1, wqkv2, wo2, wq1b, wo1b, wo2Tb, wv2Tb);
    k_camprep<<<dim3(256), dim3(256), 0, stream>>>(camr, ln2g, ln2b, wqkv1, bqkv1, wqkv2, bqkv2, kcw, vcw, uw);
    k_main<<<dim3(NGROUP), dim3(512), 0, stream>>>(pose, camr, ln1g, ln1b, bqkv1, bo1, bqkv2, bo2,
                                                   wq1b, wo1b, wo2Tb, wv2Tb, kcw, vcw, uw, out);
}

// Round 2
// 373.434 us; speedup vs baseline: 1.5854x; 1.5854x over previous
//
#include <hip/hip_runtime.h>
#include <hip/hip_bf16.h>
#include <cstdint>
#include <cstddef>

#define NGROUP 2048          // B*T*K
#define NROW   96            // P*J
#define SCALE1 0.17677669529663687f   // 1/sqrt(32)
#define POSE_ELEMS 50331648ll

typedef __attribute__((ext_vector_type(8))) short bf16x8;
typedef __attribute__((ext_vector_type(4))) float f32x4;

__device__ __forceinline__ unsigned short f2b(float f){
    unsigned int u = __float_as_uint(f);
    u = (u + 0x7FFFu + ((u >> 16) & 1u)) >> 16;   // RNE
    return (unsigned short)u;
}
__device__ __forceinline__ float b2f(unsigned short s){
    return __uint_as_float(((unsigned int)s) << 16);
}
__device__ __forceinline__ float wredsum(float v){
    #pragma unroll
    for (int m = 1; m < 64; m <<= 1) v += __shfl_xor(v, m);
    return v;
}

// ---------- K0: weights to bf16, natural row-major (for vectorized row reads) ----------
__global__ __launch_bounds__(256) void k_conv(
    const float* __restrict__ wqkv2, const float* __restrict__ wo2,
    unsigned short* __restrict__ wv2b, unsigned short* __restrict__ wo2b)
{
    int t = blockIdx.x * 256 + threadIdx.x;     // 65536
    wv2b[t] = f2b(wqkv2[131072 + t]);           // wv2 rows 512..767, natural [m][i]
    wo2b[t] = f2b(wo2[t]);                      // natural [c][m]
}

// ---------- K1: per-(b,t) prep: ck, cb1, wv_oT, u ----------
// ck[n=h*8+kk][c]   = sum_j wq1[h*32+j][c] * kc[kk][h*32+j]          (bf16)
// cb1[n]            = sum_j bq1[h*32+j]    * kc[kk][h*32+j]          (f32)
// wv_oT[c][n]       = sum_j vc[kk][h*32+j] * wo1[c][h*32+j]          (bf16)
// u[g=bt*8+r][h][i] = sum_d q2[r][h*32+d]  * wk2[h*32+d][i]          (bf16)
__global__ __launch_bounds__(256) void k_prep(
    const float* __restrict__ cam, const float* __restrict__ ln2g, const float* __restrict__ ln2b,
    const float* __restrict__ wqkv1, const float* __restrict__ bqkv1, const float* __restrict__ wo1,
    const float* __restrict__ wqkv2, const float* __restrict__ bqkv2,
    unsigned short* __restrict__ ckb, unsigned short* __restrict__ wv_oTb,
    float* __restrict__ cb1w, unsigned short* __restrict__ uwb)
{
    __shared__ float c[8][256];
    __shared__ float cn[8][256];
    __shared__ float q2s[8][256];
    __shared__ float kcs[8][256];
    __shared__ float vcs[8][256];
    int tid = threadIdx.x;
    int bt = blockIdx.x >> 1;
    int hb = (blockIdx.x & 1) * 4;          // this block handles heads hb..hb+3
    int wid = tid >> 6, lane = tid & 63;

    for (int e = tid; e < 2048; e += 256) ((float*)c)[e] = cam[(size_t)bt*2048 + e];
    __syncthreads();
    for (int r = wid; r < 8; r += 4){
        int j = lane * 4;
        float v0=c[r][j], v1=c[r][j+1], v2=c[r][j+2], v3=c[r][j+3];
        float s  = wredsum(v0+v1+v2+v3);
        float s2 = wredsum(v0*v0+v1*v1+v2*v2+v3*v3);
        float mu = s * (1.f/256.f);
        float rs = rsqrtf(s2*(1.f/256.f) - mu*mu + 1e-5f);
        cn[r][j]   = (v0-mu)*rs*ln2g[j]   + ln2b[j];
        cn[r][j+1] = (v1-mu)*rs*ln2g[j+1] + ln2b[j+1];
        cn[r][j+2] = (v2-mu)*rs*ln2g[j+2] + ln2b[j+2];
        cn[r][j+3] = (v3-mu)*rs*ln2g[j+3] + ln2b[j+3];
    }
    __syncthreads();
    {   // q2 / kc / vc columns (thread j owns column j)
        int j = tid;
        float aq[8] = {0,0,0,0,0,0,0,0}, ak[8] = {0,0,0,0,0,0,0,0}, av[8] = {0,0,0,0,0,0,0,0};
        const float4* wq = (const float4*)(wqkv2 + (size_t)j*256);
        const float4* wk = (const float4*)(wqkv1 + (size_t)(256+j)*256);
        const float4* wv = (const float4*)(wqkv1 + (size_t)(512+j)*256);
        for (int i4 = 0; i4 < 64; i4++){
            float4 q4 = wq[i4], k4 = wk[i4], v4 = wv[i4];
            int i = i4*4;
            #pragma unroll
            for (int r = 0; r < 8; r++){
                aq[r] += cn[r][i]*q4.x + cn[r][i+1]*q4.y + cn[r][i+2]*q4.z + cn[r][i+3]*q4.w;
                ak[r] += c[r][i]*k4.x + c[r][i+1]*k4.y + c[r][i+2]*k4.z + c[r][i+3]*k4.w;
                av[r] += c[r][i]*v4.x + c[r][i+1]*v4.y + c[r][i+2]*v4.z + c[r][i+3]*v4.w;
            }
        }
        float bq = bqkv2[j], bk = bqkv1[256+j], bv = bqkv1[512+j];
        for (int r = 0; r < 8; r++){
            q2s[r][j] = aq[r] + bq;
            kcs[r][j] = ak[r] + bk;
            vcs[r][j] = av[r] + bv;
        }
    }
    __syncthreads();
    {   // u (column i = tid, heads hb..hb+3)
        int i = tid;
        for (int h = hb; h < hb+4; h++){
            float acc8[8] = {0,0,0,0,0,0,0,0};
            for (int d = 0; d < 32; d++){
                float w = wqkv2[(size_t)(256 + h*32 + d)*256 + i];
                #pragma unroll
                for (int r = 0; r < 8; r++) acc8[r] += q2s[r][h*32+d] * w;
            }
            for (int r = 0; r < 8; r++)
                uwb[((size_t)(bt*8 + r)*8 + h)*256 + i] = f2b(acc8[r]);
        }
    }
    {   // ck (column c = tid)
        int cc = tid;
        for (int h = hb; h < hb+4; h++){
            float acck[8] = {0,0,0,0,0,0,0,0};
            for (int d = 0; d < 32; d++){
                float w = wqkv1[(size_t)(h*32+d)*256 + cc];
                #pragma unroll
                for (int kk = 0; kk < 8; kk++) acck[kk] += w * kcs[kk][h*32+d];
            }
            for (int kk = 0; kk < 8; kk++)
                ckb[((size_t)bt*64 + h*8 + kk)*256 + cc] = f2b(acck[kk]);
        }
    }
    {   // wv_oT (row c = tid)
        int cc = tid;
        for (int h = hb; h < hb+4; h++){
            const float4* wr = (const float4*)(wo1 + (size_t)cc*256 + h*32);
            float w[32];
            #pragma unroll
            for (int q4 = 0; q4 < 8; q4++){ float4 f = wr[q4]; w[q4*4]=f.x; w[q4*4+1]=f.y; w[q4*4+2]=f.z; w[q4*4+3]=f.w; }
            #pragma unroll
            for (int kk = 0; kk < 8; kk++){
                float a = 0.f;
                #pragma unroll
                for (int d = 0; d < 32; d++) a += w[d] * vcs[kk][h*32+d];
                wv_oTb[((size_t)bt*256 + cc)*64 + h*8 + kk] = f2b(a);
            }
        }
    }
    if (tid < 32){
        int kk = tid & 7, h = hb + (tid >> 3);
        float a = 0.f;
        for (int d = 0; d < 32; d++) a += bqkv1[h*32+d] * kcs[kk][h*32+d];
        cb1w[(size_t)bt*64 + h*8 + kk] = a;
    }
}

// ---------- K2: fused per-(b,t,k) block ----------
__global__ __launch_bounds__(512, 4) void k_main(
    const float* __restrict__ pose, const float* __restrict__ cam,
    const float* __restrict__ ln1g, const float* __restrict__ ln1b,
    const float* __restrict__ bo1, const float* __restrict__ bqkv2, const float* __restrict__ bo2,
    const unsigned short* __restrict__ ckb, const unsigned short* __restrict__ wv_oTb,
    const float* __restrict__ cb1w, const unsigned short* __restrict__ uwb,
    const unsigned short* __restrict__ wv2b, const unsigned short* __restrict__ wo2b,
    float* __restrict__ out)
{
    __shared__ __align__(16) unsigned short Xs[96*256];   // swizzled: byte^=((row&7)<<4)
    __shared__ __align__(16) unsigned short usb[16][264]; // rows 0-7 = u, 8-15 garbage (unused rows of MFMA)
    __shared__ __align__(16) float sc[8][96];
    __shared__ __align__(16) char U[13824];               // union: A1[96][72]bf16 | {A2[16][104]bf16, ys[8][260]f32, o2s[256]f32}

    int tid = threadIdx.x;
    int g = blockIdx.x;
    int bt = g >> 3;
    int wid = tid >> 6, lane = tid & 63;
    int fr = lane & 15, hi4 = lane >> 4, fk = hi4 * 8;

    // P0: u -> LDS
    {
        int e = tid * 4;
        *(ushort4*)&usb[e >> 8][e & 255] = *(const ushort4*)(uwb + (size_t)g * 2048 + e);
    }

    // P1: LN(pose) -> Xs
    {
        float4 g1 = ((const float4*)ln1g)[lane];
        float4 b1 = ((const float4*)ln1b)[lane];
        const float4* pr4 = (const float4*)(pose + (size_t)g * 96 * 256);
        float4 xv[12];
        #pragma unroll
        for (int rr = 0; rr < 12; rr++)
            xv[rr] = pr4[(size_t)(wid + rr*8) * 64 + lane];
        #pragma unroll
        for (int rr = 0; rr < 12; rr++){
            int r = wid + rr*8;
            float4 f = xv[rr];
            float s  = wredsum(f.x+f.y+f.z+f.w);
            float s2 = wredsum(f.x*f.x+f.y*f.y+f.z*f.z+f.w*f.w);
            float mu = s * (1.f/256.f);
            float rs = rsqrtf(s2*(1.f/256.f) - mu*mu + 1e-5f);
            ushort4 qv;
            qv.x = f2b((f.x-mu)*rs*g1.x + b1.x);
            qv.y = f2b((f.y-mu)*rs*g1.y + b1.y);
            qv.z = f2b((f.z-mu)*rs*g1.z + b1.z);
            qv.w = f2b((f.w-mu)*rs*g1.w + b1.w);
            *(ushort4*)((char*)Xs + r*512 + ((lane*8) ^ ((r&7)<<4))) = qv;
        }
    }
    __syncthreads();   // b1

    int wm = wid >> 2, wn = wid & 3;
    unsigned short* A1 = (unsigned short*)U;              // [96][72]

    // P2+P3: score GEMM (96x64, K=256) + softmax over kk -> A1
    {
        const unsigned short* ckg = ckb + ((size_t)bt*64 + wn*16 + fr) * 256;
        float cb = cb1w[(size_t)bt*64 + wn*16 + fr];
        f32x4 acc[3];
        #pragma unroll
        for (int mt = 0; mt < 3; mt++) acc[mt] = (f32x4){0.f,0.f,0.f,0.f};
        for (int k0 = 0; k0 < 256; k0 += 32){
            bf16x8 b = *(const bf16x8*)(ckg + k0 + fk);
            #pragma unroll
            for (int mt = 0; mt < 3; mt++){
                int r = wm*48 + mt*16 + fr;
                bf16x8 a = *(const bf16x8*)((char*)Xs + r*512 + (((k0+fk)*2) ^ ((r&7)<<4)));
                acc[mt] = __builtin_amdgcn_mfma_f32_16x16x32_bf16(a, b, acc[mt], 0, 0, 0);
            }
        }
        #pragma unroll
        for (int mt = 0; mt < 3; mt++){
            #pragma unroll
            for (int i = 0; i < 4; i++){
                float s = (acc[mt][i] + cb) * SCALE1;          // col n=wn*16+fr, kk=n&7=lane&7
                float mx = s;
                mx = fmaxf(mx, __shfl_xor(mx, 1));
                mx = fmaxf(mx, __shfl_xor(mx, 2));
                mx = fmaxf(mx, __shfl_xor(mx, 4));
                float e = __expf(s - mx);
                float sm = e;
                sm += __shfl_xor(sm, 1);
                sm += __shfl_xor(sm, 2);
                sm += __shfl_xor(sm, 4);
                int row = wm*48 + mt*16 + hi4*4 + i;
                A1[row*72 + wn*16 + fr] = f2b(e / sm);
            }
        }
    }
    __syncthreads();   // b2

    // P4: PV GEMM (96x256, K=64) + bias + residual -> out, Xs(=pose_out bf16)
    {
        const unsigned short* wvg = wv_oTb + (size_t)bt * 256 * 64;
        f32x4 acc2[3][4];
        #pragma unroll
        for (int mt = 0; mt < 3; mt++)
            #pragma unroll
            for (int nt = 0; nt < 4; nt++) acc2[mt][nt] = (f32x4){0.f,0.f,0.f,0.f};
        #pragma unroll
        for (int k0 = 0; k0 < 64; k0 += 32){
            bf16x8 a[3], b[4];
            #pragma unroll
            for (int mt = 0; mt < 3; mt++)
                a[mt] = *(const bf16x8*)&A1[(wm*48 + mt*16 + fr)*72 + k0 + fk];
            #pragma unroll
            for (int nt = 0; nt < 4; nt++)
                b[nt] = *(const bf16x8*)(wvg + (size_t)(wn*64 + nt*16 + fr)*64 + k0 + fk);
            #pragma unroll
            for (int mt = 0; mt < 3; mt++)
                #pragma unroll
                for (int nt = 0; nt < 4; nt++)
                    acc2[mt][nt] = __builtin_amdgcn_mfma_f32_16x16x32_bf16(a[mt], b[nt], acc2[mt][nt], 0, 0, 0);
        }
        float bias[4];
        #pragma unroll
        for (int nt = 0; nt < 4; nt++) bias[nt] = bo1[wn*64 + nt*16 + fr];
        const float* pr = pose + (size_t)g * 96 * 256;
        float* po = out + (size_t)g * 96 * 256;
        #pragma unroll
        for (int mt = 0; mt < 3; mt++)
            #pragma unroll
            for (int nt = 0; nt < 4; nt++)
                #pragma unroll
                for (int i = 0; i < 4; i++){
                    int row = wm*48 + mt*16 + hi4*4 + i;
                    int col = wn*64 + nt*16 + fr;
                    float val = acc2[mt][nt][i] + bias[nt] + pr[row*256 + col];
                    po[row*256 + col] = val;
                    *(unsigned short*)((char*)Xs + row*512 + ((col*2) ^ ((row&7)<<4))) = f2b(val);
                }
    }
    __syncthreads();   // b3

    // P6: stage-2 scores via MFMA: sc[h][n] = SCALE * u_h . pose_out_n  (waves 0-5)
    if (wid < 6){
        int n = wid*16 + fr;
        f32x4 a6 = (f32x4){0.f,0.f,0.f,0.f};
        for (int k0 = 0; k0 < 256; k0 += 32){
            bf16x8 u = *(const bf16x8*)&usb[fr][k0 + fk];
            bf16x8 x = *(const bf16x8*)((char*)Xs + n*512 + (((k0+fk)*2) ^ ((n&7)<<4)));
            a6 = __builtin_amdgcn_mfma_f32_16x16x32_bf16(u, x, a6, 0, 0, 0);
        }
        if (lane < 32){
            #pragma unroll
            for (int i = 0; i < 4; i++)
                sc[hi4*4 + i][n] = a6[i] * SCALE1;
        }
    }
    __syncthreads();   // b4

    // P7: softmax over n=96 (wave per head) -> A2 bf16 [16][104]
    unsigned short* A2 = (unsigned short*)U;
    {
        int hh = wid;
        float v0 = sc[hh][lane];
        float v1 = (lane < 32) ? sc[hh][64 + lane] : -3.0e38f;
        float mx = fmaxf(v0, v1);
        #pragma unroll
        for (int m = 1; m < 64; m <<= 1) mx = fmaxf(mx, __shfl_xor(mx, m));
        float e0 = __expf(v0 - mx);
        float e1 = (lane < 32) ? __expf(v1 - mx) : 0.f;
        float sum = wredsum(e0 + e1);
        float inv = 1.f / sum;
        A2[hh*104 + lane] = f2b(e0 * inv);
        if (lane < 32) A2[hh*104 + 64 + lane] = f2b(e1 * inv);
    }
    __syncthreads();   // b5

    // P8: y[h][c] = sum_n a2[h][n] * pose_out[n][c]  via MFMA (transposed-B gather)
    float* ys = (float*)(U + 3328);                       // [8][260]
    {
        f32x4 ay[2] = {(f32x4){0.f,0.f,0.f,0.f}, (f32x4){0.f,0.f,0.f,0.f}};
        for (int k0 = 0; k0 < 96; k0 += 32){
            bf16x8 a8 = *(const bf16x8*)&A2[fr*104 + k0 + fk];
            #pragma unroll
            for (int nt = 0; nt < 2; nt++){
                int col = wid*32 + nt*16 + fr;
                union { bf16x8 v; unsigned short u[8]; } bx;
                #pragma unroll
                for (int jj = 0; jj < 8; jj++){
                    int n = k0 + fk + jj;
                    bx.u[jj] = *(const unsigned short*)((char*)Xs + n*512 + ((col*2) ^ ((n&7)<<4)));
                }
                ay[nt] = __builtin_amdgcn_mfma_f32_16x16x32_bf16(a8, bx.v, ay[nt], 0, 0, 0);
            }
        }
        if (lane < 32){
            #pragma unroll
            for (int nt = 0; nt < 2; nt++)
                #pragma unroll
                for (int i = 0; i < 4; i++)
                    ys[(hi4*4 + i)*260 + wid*32 + nt*16 + fr] = ay[nt][i];
        }
    }
    __syncthreads();   // b6

    // P9: o2[m] = bv2[m] + wv2[m,:] . y[m>>5]
    float* o2s = (float*)(U + 3328 + 8320);
    if (tid < 256){
        int m = tid;
        const float* yr = ys + (m >> 5) * 260;
        float a = bqkv2[512 + m];
        const unsigned short* wr = wv2b + (size_t)m * 256;
        for (int c8 = 0; c8 < 32; c8++){
            bf16x8 wv = *(const bf16x8*)(wr + c8*8);
            float4 y0 = *(const float4*)(yr + c8*8);
            float4 y1 = *(const float4*)(yr + c8*8 + 4);
            a += b2f((unsigned short)wv[0])*y0.x + b2f((unsigned short)wv[1])*y0.y
               + b2f((unsigned short)wv[2])*y0.z + b2f((unsigned short)wv[3])*y0.w
               + b2f((unsigned short)wv[4])*y1.x + b2f((unsigned short)wv[5])*y1.y
               + b2f((unsigned short)wv[6])*y1.z + b2f((unsigned short)wv[7])*y1.w;
        }
        o2s[m] = a;
    }
    __syncthreads();   // b7

    // P10: cam_out = cam + bo2 + o2 @ wo2^T
    if (tid < 256){
        int cc = tid;
        float a = bo2[cc] + cam[(size_t)g*256 + cc];
        const unsigned short* wr = wo2b + (size_t)cc * 256;
        const float4* o4 = (const float4*)o2s;
        for (int m8 = 0; m8 < 32; m8++){
            bf16x8 wv = *(const bf16x8*)(wr + m8*8);
            float4 y0 = o4[m8*2], y1 = o4[m8*2+1];
            a += b2f((unsigned short)wv[0])*y0.x + b2f((unsigned short)wv[1])*y0.y
               + b2f((unsigned short)wv[2])*y0.z + b2f((unsigned short)wv[3])*y0.w
               + b2f((unsigned short)wv[4])*y1.x + b2f((unsigned short)wv[5])*y1.y
               + b2f((unsigned short)wv[6])*y1.z + b2f((unsigned short)wv[7])*y1.w;
        }
        out[POSE_ELEMS + (size_t)g*256 + cc] = a;
    }
}

extern "C" void kernel_launch(void* const* d_in, const int* in_sizes, int n_in,
                              void* d_out, int out_size, void* d_ws, size_t ws_size,
                              hipStream_t stream)
{
    const float* pose  = (const float*)d_in[0];
    const float* camr  = (const float*)d_in[1];
    const float* ln1g  = (const float*)d_in[2];
    const float* ln1b  = (const float*)d_in[3];
    const float* wqkv1 = (const float*)d_in[4];
    const float* bqkv1 = (const float*)d_in[5];
    const float* wo1   = (const float*)d_in[6];
    const float* bo1   = (const float*)d_in[7];
    const float* ln2g  = (const float*)d_in[8];
    const float* ln2b  = (const float*)d_in[9];
    const float* wqkv2 = (const float*)d_in[10];
    const float* bqkv2 = (const float*)d_in[11];
    const float* wo2   = (const float*)d_in[12];
    const float* bo2   = (const float*)d_in[13];
    float* out = (float*)d_out;
    char* ws = (char*)d_ws;

    unsigned short* wv2b   = (unsigned short*)ws;                         // 131072 B
    unsigned short* wo2b   = (unsigned short*)(ws + 131072);              // 131072 B
    unsigned short* ckb    = (unsigned short*)(ws + 262144);              // 8 MB
    unsigned short* wv_oTb = (unsigned short*)(ws + 262144 + 8388608);    // 8 MB
    unsigned short* uwb    = (unsigned short*)(ws + 262144 + 2*8388608);  // 8 MB
    float*          cb1w   = (float*)(ws + 262144 + 3*8388608);           // 64 KB

    k_conv<<<dim3(256), dim3(256), 0, stream>>>(wqkv2, wo2, wv2b, wo2b);
    k_prep<<<dim3(512), dim3(256), 0, stream>>>(camr, ln2g, ln2b, wqkv1, bqkv1, wo1,
                                                wqkv2, bqkv2, ckb, wv_oTb, cb1w, uwb);
    k_main<<<dim3(NGROUP), dim3(512), 0, stream>>>(pose, camr, ln1g, ln1b, bo1, bqkv2, bo2,
                                                   ckb, wv_oTb, cb1w, uwb, wv2b, wo2b, out);
}

// Round 3
// 266.043 us; speedup vs baseline: 2.2254x; 1.4037x over previous
//
#include <hip/hip_runtime.h>
#include <hip/hip_bf16.h>
#include <cstdint>
#include <cstddef>

#define NGROUP 2048          // B*T*K
#define SCALE1 0.17677669529663687f   // 1/sqrt(32)
#define POSE_ELEMS 50331648ll

typedef __attribute__((ext_vector_type(8))) short bf16x8;
typedef __attribute__((ext_vector_type(4))) float f32x4;

__device__ __forceinline__ unsigned short f2b(float f){
    unsigned int u = __float_as_uint(f);
    u = (u + 0x7FFFu + ((u >> 16) & 1u)) >> 16;   // RNE
    return (unsigned short)u;
}
__device__ __forceinline__ float b2f(unsigned short s){
    return __uint_as_float(((unsigned int)s) << 16);
}
__device__ __forceinline__ float wredsum(float v){
    #pragma unroll
    for (int m = 1; m < 64; m <<= 1) v += __shfl_xor(v, m);
    return v;
}

// ---------- K0: all weights -> bf16 in GEMM-ready layouts ----------
__global__ __launch_bounds__(256) void k_conv2(
    const float* __restrict__ wqkv1, const float* __restrict__ wo1,
    const float* __restrict__ wqkv2, const float* __restrict__ wo2,
    unsigned short* __restrict__ wk1b,  unsigned short* __restrict__ wv1b,
    unsigned short* __restrict__ wq2b,  unsigned short* __restrict__ wq1Tb,
    unsigned short* __restrict__ wk2Tb, unsigned short* __restrict__ wo1b,
    unsigned short* __restrict__ wv2b,  unsigned short* __restrict__ wo2b)
{
    int t = blockIdx.x * 256 + threadIdx.x;     // 65536
    int r = t >> 8, c = t & 255;
    wk1b[t] = f2b(wqkv1[(size_t)(256+r)*256 + c]);
    wv1b[t] = f2b(wqkv1[(size_t)(512+r)*256 + c]);
    wq2b[t] = f2b(wqkv2[t]);
    wo1b[t] = f2b(wo1[t]);
    wv2b[t] = f2b(wqkv2[(size_t)(512+r)*256 + c]);
    wo2b[t] = f2b(wo2[t]);
    // transposed layouts (coalesced read, scattered 2B write -> L2 combines)
    wq1Tb[(size_t)c*256 + r] = f2b(wqkv1[t]);                       // wq1T[c][j]
    wk2Tb[(size_t)c*256 + r] = f2b(wqkv2[(size_t)(256+r)*256 + c]); // wk2T[i][d]
}

// ---------- K1: MFMA prep. Block = 32 camera rows (4 bt). ----------
// Phase A: LN -> camb/cnb (bf16 LDS). Phase B: kc/vc/q2 (M32,N256,K256) -> LDS.
// Phase C: per-head ck/u/wv_o (M32,N256,K32) -> global ws; cb1 via VALU.
__global__ __launch_bounds__(512) void k_prep2(
    const float* __restrict__ cam, const float* __restrict__ ln2g, const float* __restrict__ ln2b,
    const float* __restrict__ bqkv1, const float* __restrict__ bqkv2,
    const unsigned short* __restrict__ wk1b,  const unsigned short* __restrict__ wv1b,
    const unsigned short* __restrict__ wq2b,  const unsigned short* __restrict__ wq1Tb,
    const unsigned short* __restrict__ wk2Tb, const unsigned short* __restrict__ wo1b,
    unsigned short* __restrict__ ckb, unsigned short* __restrict__ wv_oTb,
    unsigned short* __restrict__ uwb, float* __restrict__ cb1w)
{
    __shared__ unsigned short camb[32*264];
    __shared__ unsigned short cnb [32*264];
    __shared__ unsigned short kcs [32*264];
    __shared__ unsigned short vcs [32*264];
    __shared__ unsigned short q2s [32*264];

    int tid = threadIdx.x;
    int wid = tid >> 6, lane = tid & 63;
    int fr = lane & 15, hi4 = lane >> 4, fk = hi4 * 8;
    int r0 = blockIdx.x * 32;                   // camera rows r0..r0+31 (bt = r0/8 ..)

    // Phase A: load cam, LN, write raw+ln bf16
    {
        float4 g2 = ((const float4*)ln2g)[lane];
        float4 b2 = ((const float4*)ln2b)[lane];
        #pragma unroll
        for (int rr = 0; rr < 4; rr++){
            int row = wid*4 + rr;
            float4 f = ((const float4*)(cam + (size_t)(r0+row)*256))[lane];
            float s  = wredsum(f.x+f.y+f.z+f.w);
            float s2 = wredsum(f.x*f.x+f.y*f.y+f.z*f.z+f.w*f.w);
            float mu = s * (1.f/256.f);
            float rs = rsqrtf(s2*(1.f/256.f) - mu*mu + 1e-5f);
            ushort4 rawv, lnv;
            rawv.x = f2b(f.x); rawv.y = f2b(f.y); rawv.z = f2b(f.z); rawv.w = f2b(f.w);
            lnv.x = f2b((f.x-mu)*rs*g2.x + b2.x);
            lnv.y = f2b((f.y-mu)*rs*g2.y + b2.y);
            lnv.z = f2b((f.z-mu)*rs*g2.z + b2.z);
            lnv.w = f2b((f.w-mu)*rs*g2.w + b2.w);
            *(ushort4*)&camb[row*264 + lane*4] = rawv;
            *(ushort4*)&cnb [row*264 + lane*4] = lnv;
        }
    }
    __syncthreads();

    // Phase B: 3 GEMMs (kc, vc, q2), M=32 N=256 K=256, bias-added, bf16 -> LDS
    for (int u = wid; u < 96; u += 8){
        int gm = u >> 5;                 // 0=kc 1=vc 2=q2
        int rem = u & 31, mt = rem >> 4, nt = rem & 15;
        const unsigned short* As = (gm == 2) ? cnb : camb;
        const unsigned short* Bw = (gm == 0) ? wk1b : (gm == 1) ? wv1b : wq2b;
        const float* bias = (gm == 0) ? (bqkv1 + 256) : (gm == 1) ? (bqkv1 + 512) : bqkv2;
        unsigned short* Dst = (gm == 0) ? kcs : (gm == 1) ? vcs : q2s;
        int col = nt*16 + fr;
        float bc = bias[col];
        f32x4 acc = (f32x4){0.f,0.f,0.f,0.f};
        for (int k0 = 0; k0 < 256; k0 += 32){
            bf16x8 a = *(const bf16x8*)&As[(mt*16 + fr)*264 + k0 + fk];
            bf16x8 b = *(const bf16x8*)&Bw[(size_t)col*256 + k0 + fk];
            acc = __builtin_amdgcn_mfma_f32_16x16x32_bf16(a, b, acc, 0, 0, 0);
        }
        #pragma unroll
        for (int i = 0; i < 4; i++)
            Dst[(mt*16 + hi4*4 + i)*264 + col] = f2b(acc[i] + bc);
    }
    __syncthreads();

    // Phase C: per-head GEMMs -> global
    for (int u = wid; u < 48; u += 8){
        int ot = u >> 4;                  // 0=ck 1=u 2=wv_o
        int rem = u & 15, h = rem >> 1, mt = rem & 1;
        const unsigned short* As = (ot == 0) ? kcs : (ot == 1) ? q2s : vcs;
        const unsigned short* Bw = (ot == 0) ? wq1Tb : (ot == 1) ? wk2Tb : wo1b;
        bf16x8 a = *(const bf16x8*)&As[(mt*16 + fr)*264 + h*32 + fk];
        int rbase = mt*16 + hi4*4;        // rows rbase..rbase+3
        int btl = rbase >> 3, kkb = rbase & 7;
        for (int nt = 0; nt < 16; nt++){
            int col = nt*16 + fr;
            bf16x8 b = *(const bf16x8*)&Bw[(size_t)col*256 + h*32 + fk];
            f32x4 acc = __builtin_amdgcn_mfma_f32_16x16x32_bf16(a, b, (f32x4){0.f,0.f,0.f,0.f}, 0, 0, 0);
            if (ot == 0){
                size_t base = ((size_t)(r0/8 + btl)*64 + h*8 + kkb)*256 + col;
                #pragma unroll
                for (int i = 0; i < 4; i++) ckb[base + (size_t)i*256] = f2b(acc[i]);
            } else if (ot == 1){
                size_t base = ((size_t)(r0 + btl*8 + kkb))*2048 + h*256 + col;
                #pragma unroll
                for (int i = 0; i < 4; i++) uwb[base + (size_t)i*2048] = f2b(acc[i]);
            } else {
                ushort4 wv;
                wv.x = f2b(acc[0]); wv.y = f2b(acc[1]); wv.z = f2b(acc[2]); wv.w = f2b(acc[3]);
                *(ushort4*)&wv_oTb[((size_t)(r0/8 + btl)*256 + col)*64 + h*8 + kkb] = wv;
            }
        }
    }
    // cb1[bt][h*8+kk] = sum_j bq1[h*32+j] * kc_bf16[btl*8+kk][h*32+j]
    if (tid < 256){
        int btl = tid >> 6, n = tid & 63, h = n >> 3, kk = n & 7;
        float a = 0.f;
        for (int j = 0; j < 32; j++)
            a += bqkv1[h*32 + j] * b2f(kcs[(btl*8 + kk)*264 + h*32 + j]);
        cb1w[(size_t)(r0/8 + btl)*64 + n] = a;
    }
}

// ---------- K2: fused per-(b,t,k) block ----------
__global__ __launch_bounds__(512, 4) void k_main(
    const float* __restrict__ pose, const float* __restrict__ cam,
    const float* __restrict__ ln1g, const float* __restrict__ ln1b,
    const float* __restrict__ bo1, const float* __restrict__ bqkv2, const float* __restrict__ bo2,
    const unsigned short* __restrict__ ckb, const unsigned short* __restrict__ wv_oTb,
    const float* __restrict__ cb1w, const unsigned short* __restrict__ uwb,
    const unsigned short* __restrict__ wv2b, const unsigned short* __restrict__ wo2b,
    float* __restrict__ out)
{
    __shared__ __align__(16) unsigned short Xs[96*256];   // swizzled: byte^=((row&7)<<4)
    __shared__ __align__(16) unsigned short usb[16][264];
    __shared__ __align__(16) float sc[8][96];
    __shared__ __align__(16) char U[13824];               // A1[96][72] | {A2[16][104], ys[8][260], o2s[256]}

    int tid = threadIdx.x;
    int g = blockIdx.x;
    int bt = g >> 3;
    int wid = tid >> 6, lane = tid & 63;
    int fr = lane & 15, hi4 = lane >> 4, fk = hi4 * 8;

    // P0: u -> LDS
    {
        int e = tid * 4;
        *(ushort4*)&usb[e >> 8][e & 255] = *(const ushort4*)(uwb + (size_t)g * 2048 + e);
    }

    // P1: LN(pose) -> Xs; pose kept in xv registers for the residual
    float4 xv[12];
    {
        float4 g1 = ((const float4*)ln1g)[lane];
        float4 b1 = ((const float4*)ln1b)[lane];
        const float4* pr4 = (const float4*)(pose + (size_t)g * 96 * 256);
        #pragma unroll
        for (int rr = 0; rr < 12; rr++)
            xv[rr] = pr4[(size_t)(wid + rr*8) * 64 + lane];
        #pragma unroll
        for (int rr = 0; rr < 12; rr++){
            int r = wid + rr*8;
            float4 f = xv[rr];
            float s  = wredsum(f.x+f.y+f.z+f.w);
            float s2 = wredsum(f.x*f.x+f.y*f.y+f.z*f.z+f.w*f.w);
            float mu = s * (1.f/256.f);
            float rs = rsqrtf(s2*(1.f/256.f) - mu*mu + 1e-5f);
            ushort4 qv;
            qv.x = f2b((f.x-mu)*rs*g1.x + b1.x);
            qv.y = f2b((f.y-mu)*rs*g1.y + b1.y);
            qv.z = f2b((f.z-mu)*rs*g1.z + b1.z);
            qv.w = f2b((f.w-mu)*rs*g1.w + b1.w);
            *(ushort4*)((char*)Xs + r*512 + ((lane*8) ^ ((r&7)<<4))) = qv;
        }
    }
    __syncthreads();   // b1

    int wm = wid >> 2, wn = wid & 3;
    unsigned short* A1 = (unsigned short*)U;              // [96][72]

    // P2+P3: score GEMM (96x64, K=256) + softmax over kk -> A1
    {
        const unsigned short* ckg = ckb + ((size_t)bt*64 + wn*16 + fr) * 256;
        float cb = cb1w[(size_t)bt*64 + wn*16 + fr];
        f32x4 acc[3];
        #pragma unroll
        for (int mt = 0; mt < 3; mt++) acc[mt] = (f32x4){0.f,0.f,0.f,0.f};
        for (int k0 = 0; k0 < 256; k0 += 32){
            bf16x8 b = *(const bf16x8*)(ckg + k0 + fk);
            #pragma unroll
            for (int mt = 0; mt < 3; mt++){
                int r = wm*48 + mt*16 + fr;
                bf16x8 a = *(const bf16x8*)((char*)Xs + r*512 + (((k0+fk)*2) ^ ((r&7)<<4)));
                acc[mt] = __builtin_amdgcn_mfma_f32_16x16x32_bf16(a, b, acc[mt], 0, 0, 0);
            }
        }
        #pragma unroll
        for (int mt = 0; mt < 3; mt++){
            #pragma unroll
            for (int i = 0; i < 4; i++){
                float s = (acc[mt][i] + cb) * SCALE1;
                float mx = s;
                mx = fmaxf(mx, __shfl_xor(mx, 1));
                mx = fmaxf(mx, __shfl_xor(mx, 2));
                mx = fmaxf(mx, __shfl_xor(mx, 4));
                float e = __expf(s - mx);
                float sm = e;
                sm += __shfl_xor(sm, 1);
                sm += __shfl_xor(sm, 2);
                sm += __shfl_xor(sm, 4);
                int row = wm*48 + mt*16 + hi4*4 + i;
                A1[row*72 + wn*16 + fr] = f2b(e / sm);
            }
        }
    }
    __syncthreads();   // b2

    // P4: PV GEMM (96x256, K=64): o1 = A1 @ wv_o + bo1 -> Xs (bf16), nt-split for regs
    {
        const unsigned short* wvg = wv_oTb + (size_t)bt * 256 * 64;
        #pragma unroll
        for (int half = 0; half < 2; half++){
            f32x4 acc2[3][2];
            #pragma unroll
            for (int mt = 0; mt < 3; mt++)
                #pragma unroll
                for (int j = 0; j < 2; j++) acc2[mt][j] = (f32x4){0.f,0.f,0.f,0.f};
            #pragma unroll
            for (int k0 = 0; k0 < 64; k0 += 32){
                bf16x8 a[3], b[2];
                #pragma unroll
                for (int mt = 0; mt < 3; mt++)
                    a[mt] = *(const bf16x8*)&A1[(wm*48 + mt*16 + fr)*72 + k0 + fk];
                #pragma unroll
                for (int j = 0; j < 2; j++)
                    b[j] = *(const bf16x8*)(wvg + (size_t)(wn*64 + (half*2+j)*16 + fr)*64 + k0 + fk);
                #pragma unroll
                for (int mt = 0; mt < 3; mt++)
                    #pragma unroll
                    for (int j = 0; j < 2; j++)
                        acc2[mt][j] = __builtin_amdgcn_mfma_f32_16x16x32_bf16(a[mt], b[j], acc2[mt][j], 0, 0, 0);
            }
            #pragma unroll
            for (int j = 0; j < 2; j++){
                int col = wn*64 + (half*2+j)*16 + fr;
                float bias = bo1[col];
                #pragma unroll
                for (int mt = 0; mt < 3; mt++)
                    #pragma unroll
                    for (int i = 0; i < 4; i++){
                        int row = wm*48 + mt*16 + hi4*4 + i;
                        *(unsigned short*)((char*)Xs + row*512 + ((col*2) ^ ((row&7)<<4))) = f2b(acc2[mt][j][i] + bias);
                    }
            }
        }
    }
    __syncthreads();   // b3

    // P5: residual pass (P1 mapping): out = pose(regs) + o1(Xs); Xs <- pose_out bf16
    {
        float* po = out + (size_t)g * 96 * 256;
        #pragma unroll
        for (int rr = 0; rr < 12; rr++){
            int r = wid + rr*8;
            char* px = (char*)Xs + r*512 + ((lane*8) ^ ((r&7)<<4));
            ushort4 ov = *(ushort4*)px;
            float4 f = xv[rr];
            float4 val;
            val.x = f.x + b2f(ov.x);
            val.y = f.y + b2f(ov.y);
            val.z = f.z + b2f(ov.z);
            val.w = f.w + b2f(ov.w);
            *(float4*)(po + (size_t)r*256 + lane*4) = val;
            ushort4 nv;
            nv.x = f2b(val.x); nv.y = f2b(val.y); nv.z = f2b(val.z); nv.w = f2b(val.w);
            *(ushort4*)px = nv;
        }
    }
    __syncthreads();   // b4

    // P6: stage-2 scores via MFMA: sc[h][n] = SCALE * u_h . pose_out_n (waves 0-5)
    if (wid < 6){
        int n = wid*16 + fr;
        f32x4 a6 = (f32x4){0.f,0.f,0.f,0.f};
        for (int k0 = 0; k0 < 256; k0 += 32){
            bf16x8 u = *(const bf16x8*)&usb[fr][k0 + fk];
            bf16x8 x = *(const bf16x8*)((char*)Xs + n*512 + (((k0+fk)*2) ^ ((n&7)<<4)));
            a6 = __builtin_amdgcn_mfma_f32_16x16x32_bf16(u, x, a6, 0, 0, 0);
        }
        if (lane < 32){
            #pragma unroll
            for (int i = 0; i < 4; i++)
                sc[hi4*4 + i][n] = a6[i] * SCALE1;
        }
    }
    __syncthreads();   // b5

    // P7: softmax over n=96 (wave per head) -> A2 bf16 [16][104]
    unsigned short* A2 = (unsigned short*)U;
    {
        int hh = wid;
        float v0 = sc[hh][lane];
        float v1 = (lane < 32) ? sc[hh][64 + lane] : -3.0e38f;
        float mx = fmaxf(v0, v1);
        #pragma unroll
        for (int m = 1; m < 64; m <<= 1) mx = fmaxf(mx, __shfl_xor(mx, m));
        float e0 = __expf(v0 - mx);
        float e1 = (lane < 32) ? __expf(v1 - mx) : 0.f;
        float sum = wredsum(e0 + e1);
        float inv = 1.f / sum;
        A2[hh*104 + lane] = f2b(e0 * inv);
        if (lane < 32) A2[hh*104 + 64 + lane] = f2b(e1 * inv);
    }
    __syncthreads();   // b6

    // P8: y[h][c] = sum_n a2[h][n] * pose_out[n][c] via MFMA (transposed-B gather)
    float* ys = (float*)(U + 3328);                       // [8][260]
    {
        f32x4 ay[2] = {(f32x4){0.f,0.f,0.f,0.f}, (f32x4){0.f,0.f,0.f,0.f}};
        for (int k0 = 0; k0 < 96; k0 += 32){
            bf16x8 a8 = *(const bf16x8*)&A2[fr*104 + k0 + fk];
            #pragma unroll
            for (int nt = 0; nt < 2; nt++){
                int col = wid*32 + nt*16 + fr;
                union { bf16x8 v; unsigned short u[8]; } bx;
                #pragma unroll
                for (int jj = 0; jj < 8; jj++){
                    int n = k0 + fk + jj;
                    bx.u[jj] = *(const unsigned short*)((char*)Xs + n*512 + ((col*2) ^ ((n&7)<<4)));
                }
                ay[nt] = __builtin_amdgcn_mfma_f32_16x16x32_bf16(a8, bx.v, ay[nt], 0, 0, 0);
            }
        }
        if (lane < 32){
            #pragma unroll
            for (int nt = 0; nt < 2; nt++)
                #pragma unroll
                for (int i = 0; i < 4; i++)
                    ys[(hi4*4 + i)*260 + wid*32 + nt*16 + fr] = ay[nt][i];
        }
    }
    __syncthreads();   // b7

    // P9: o2[m] = bv2[m] + wv2[m,:] . y[m>>5]
    float* o2s = (float*)(U + 3328 + 8320);
    if (tid < 256){
        int m = tid;
        const float* yr = ys + (m >> 5) * 260;
        float a = bqkv2[512 + m];
        const unsigned short* wr = wv2b + (size_t)m * 256;
        for (int c8 = 0; c8 < 32; c8++){
            bf16x8 wv = *(const bf16x8*)(wr + c8*8);
            float4 y0 = *(const float4*)(yr + c8*8);
            float4 y1 = *(const float4*)(yr + c8*8 + 4);
            a += b2f((unsigned short)wv[0])*y0.x + b2f((unsigned short)wv[1])*y0.y
               + b2f((unsigned short)wv[2])*y0.z + b2f((unsigned short)wv[3])*y0.w
               + b2f((unsigned short)wv[4])*y1.x + b2f((unsigned short)wv[5])*y1.y
               + b2f((unsigned short)wv[6])*y1.z + b2f((unsigned short)wv[7])*y1.w;
        }
        o2s[m] = a;
    }
    __syncthreads();   // b8

    // P10: cam_out = cam + bo2 + o2 @ wo2^T
    if (tid < 256){
        int cc = tid;
        float a = bo2[cc] + cam[(size_t)g*256 + cc];
        const unsigned short* wr = wo2b + (size_t)cc * 256;
        const float4* o4 = (const float4*)o2s;
        for (int m8 = 0; m8 < 32; m8++){
            bf16x8 wv = *(const bf16x8*)(wr + m8*8);
            float4 y0 = o4[m8*2], y1 = o4[m8*2+1];
            a += b2f((unsigned short)wv[0])*y0.x + b2f((unsigned short)wv[1])*y0.y
               + b2f((unsigned short)wv[2])*y0.z + b2f((unsigned short)wv[3])*y0.w
               + b2f((unsigned short)wv[4])*y1.x + b2f((unsigned short)wv[5])*y1.y
               + b2f((unsigned short)wv[6])*y1.z + b2f((unsigned short)wv[7])*y1.w;
        }
        out[POSE_ELEMS + (size_t)g*256 + cc] = a;
    }
}

extern "C" void kernel_launch(void* const* d_in, const int* in_sizes, int n_in,
                              void* d_out, int out_size, void* d_ws, size_t ws_size,
                              hipStream_t stream)
{
    const float* pose  = (const float*)d_in[0];
    const float* camr  = (const float*)d_in[1];
    const float* ln1g  = (const float*)d_in[2];
    const float* ln1b  = (const float*)d_in[3];
    const float* wqkv1 = (const float*)d_in[4];
    const float* bqkv1 = (const float*)d_in[5];
    const float* wo1   = (const float*)d_in[6];
    const float* bo1   = (const float*)d_in[7];
    const float* ln2g  = (const float*)d_in[8];
    const float* ln2b  = (const float*)d_in[9];
    const float* wqkv2 = (const float*)d_in[10];
    const float* bqkv2 = (const float*)d_in[11];
    const float* wo2   = (const float*)d_in[12];
    const float* bo2   = (const float*)d_in[13];
    float* out = (float*)d_out;
    char* ws = (char*)d_ws;

    // ws layout (25.06 MB total)
    unsigned short* ckb    = (unsigned short*)ws;                      // 8 MB
    unsigned short* wv_oTb = (unsigned short*)(ws + 8388608);          // 8 MB
    unsigned short* uwb    = (unsigned short*)(ws + 2*8388608);        // 8 MB
    unsigned short* wts    = (unsigned short*)(ws + 3*8388608);        // 8 x 128 KB
    unsigned short* wk1b  = wts;
    unsigned short* wv1b  = wts + 1*65536;
    unsigned short* wq2b  = wts + 2*65536;
    unsigned short* wq1Tb = wts + 3*65536;
    unsigned short* wk2Tb = wts + 4*65536;
    unsigned short* wo1b  = wts + 5*65536;
    unsigned short* wv2b  = wts + 6*65536;
    unsigned short* wo2b  = wts + 7*65536;
    float* cb1w = (float*)(ws + 3*8388608 + 8*131072);                 // 64 KB

    k_conv2<<<dim3(256), dim3(256), 0, stream>>>(wqkv1, wo1, wqkv2, wo2,
                                                 wk1b, wv1b, wq2b, wq1Tb, wk2Tb, wo1b, wv2b, wo2b);
    k_prep2<<<dim3(64), dim3(512), 0, stream>>>(camr, ln2g, ln2b, bqkv1, bqkv2,
                                                wk1b, wv1b, wq2b, wq1Tb, wk2Tb, wo1b,
                                                ckb, wv_oTb, uwb, cb1w);
    k_main<<<dim3(NGROUP), dim3(512), 0, stream>>>(pose, camr, ln1g, ln1b, bo1, bqkv2, bo2,
                                                   ckb, wv_oTb, cb1w, uwb, wv2b, wo2b, out);
}